// Round 1
// 193.524 us; speedup vs baseline: 1.0429x; 1.0429x over previous
//
#include <hip/hip_runtime.h>
#include <hip/hip_bf16.h>

#define BN 4
#define CN 64
#define ON 64
#define HN 128
#define WN 128
#define HWN (HN*WN)
#define NT 9

typedef __attribute__((ext_vector_type(8))) short bf16x8;
typedef __attribute__((ext_vector_type(4))) float floatx4;

static __device__ __forceinline__ unsigned short f2bf(float f) {
    unsigned int u = __builtin_bit_cast(unsigned int, f);
    u += 0x7fffu + ((u >> 16) & 1u);   // RNE
    return (unsigned short)(u >> 16);
}

// XCD-aware swizzle for 1024 blocks: XCD k owns works [k*128, k*128+128)
// = 64 consecutive rows of one image (~2.1MB x working set < 4MB L2/XCD).
static __device__ __forceinline__ int swz_work(int b) {
    return ((b & 7) << 7) | (b >> 3);
}

// ---------------------------------------------------------------------------
// Kernel A: per-pixel lie-weight conv -> homography -> 9 (ox,oy) offsets.
// Regridded: 1024 blocks x 256 thr = 64 pixels x 4 channel-groups(16c each).
// Also transposes w_conv (O,C,3,3) -> bf16 wbf[n][o][c] for MFMA B-fragments.
// ---------------------------------------------------------------------------
__global__ __launch_bounds__(256) void offsets_kernel(
    const float* __restrict__ x, const float* __restrict__ w_off,
    const float* __restrict__ w_conv,
    const float* __restrict__ P, const float* __restrict__ d,
    const float* __restrict__ Pinv,
    float2* __restrict__ offs, unsigned short* __restrict__ wbf)
{
    const int tid = threadIdx.x;
    __shared__ float swoff[CN*NT];     // 2304 B
    __shared__ float sred[4][64];      // 1024 B
    __shared__ float sHm[64][10];      // 2560 B (9 used, +1 pad)

    for (int i = tid; i < CN*NT; i += 256) swoff[i] = w_off[i];

    // w_conv -> bf16 transposed copy (first 36864 global threads, raw idx)
    int gid = blockIdx.x * 256 + tid;
    if (gid < ON*CN*NT) {
        int o   = gid / (CN*NT);
        int rem = gid - o*(CN*NT);
        int c   = rem / NT;
        int n   = rem - c*NT;
        wbf[(n*ON + o)*CN + c] = f2bf(w_conv[gid]);
    }

    const int work  = swz_work(blockIdx.x);
    const int pbase = work << 6;               // 64 pixels per block
    const int pix   = tid & 63;
    const int cg    = tid >> 6;                // channel group 0..3
    const int p     = pbase + pix;
    const int wi    = p & (WN-1);
    const int hi    = (p >> 7) & (HN-1);
    const int bi    = p >> 14;
    const float* xb   = x + (size_t)bi*CN*HWN + (size_t)(cg*16)*HWN;
    const float* swc0 = &swoff[cg*16*NT];

    __syncthreads();                           // swoff ready

    float accv = 0.f;
    #pragma unroll
    for (int ky = 0; ky < 3; ++ky) {
        int yy = hi + ky - 1;
        #pragma unroll
        for (int kx = 0; kx < 3; ++kx) {
            int xx = wi + kx - 1;
            bool v  = (yy >= 0) && (yy < HN) && (xx >= 0) && (xx < WN);
            float m = v ? 1.f : 0.f;
            int a   = v ? (yy*WN + xx) : 0;
            const float* swc = swc0 + (ky*3 + kx);
            float t0 = 0.f, t1 = 0.f, t2 = 0.f, t3 = 0.f;
            #pragma unroll
            for (int c = 0; c < 16; c += 4) {
                t0 = fmaf(xb[(size_t)(c+0)*HWN + a], swc[(c+0)*NT], t0);
                t1 = fmaf(xb[(size_t)(c+1)*HWN + a], swc[(c+1)*NT], t1);
                t2 = fmaf(xb[(size_t)(c+2)*HWN + a], swc[(c+2)*NT], t2);
                t3 = fmaf(xb[(size_t)(c+3)*HWN + a], swc[(c+3)*NT], t3);
            }
            accv = fmaf(m, (t0+t1)+(t2+t3), accv);
        }
    }
    sred[cg][pix] = accv;
    __syncthreads();

    if (tid < 64) {
        float raw = (sred[0][tid]+sred[1][tid]) + (sred[2][tid]+sred[3][tid]);
        float lw  = fminf(fmaxf(raw + 0.5f, 0.f), 1.f);
        float pw[3];
        #pragma unroll
        for (int k = 0; k < 3; ++k) pw[k] = exp2f(lw * log2f(d[k]));
        #pragma unroll
        for (int i = 0; i < 3; ++i)
            #pragma unroll
            for (int j = 0; j < 3; ++j)
                sHm[tid][i*3+j] = P[i*3+0]*pw[0]*Pinv[0+j]
                                + P[i*3+1]*pw[1]*Pinv[3+j]
                                + P[i*3+2]*pw[2]*Pinv[6+j];
    }
    __syncthreads();

    // coalesced offs write: consecutive e -> consecutive float2
    for (int e = tid; e < 64*NT; e += 256) {
        int pp = e / NT, n = e - pp*NT;
        float fx = (float)(n % 3) - 1.f;
        float fy = (float)(n / 3) - 1.f;
        float qx = sHm[pp][0]*fx + sHm[pp][1]*fy + sHm[pp][2];
        float qy = sHm[pp][3]*fx + sHm[pp][4]*fy + sHm[pp][5];
        float qz = sHm[pp][6]*fx + sHm[pp][7]*fy + sHm[pp][8];
        float ri = 1.f / qz;
        offs[(size_t)(pbase+pp)*NT + n] = make_float2(qx*ri, qy*ri);
    }
}

// ---------------------------------------------------------------------------
// Kernel B: 64 pixels/block (one half-row). Per n-chunk: bilinear-gather a
// 64pix x 64c bf16 tile into LDS, then MFMA 16x16x32_bf16 against wbf[n].
// Swizzled so each XCD's gathers stay in its own L2.
// ---------------------------------------------------------------------------
#define LDS_BYTES 27648   // tapA 9216 | tapW 9216 | sTile 9216 (64 x 72 bf16)

__global__ __launch_bounds__(256) void deform_kernel(
    const float* __restrict__ x, const float2* __restrict__ offs,
    const unsigned short* __restrict__ wbf, float* __restrict__ out)
{
    __shared__ char lds[LDS_BYTES];
    int4*   tapA = (int4*)lds;                              // [576]
    float4* tapW = (float4*)(lds + 9216);                   // [576]
    unsigned short* sT = (unsigned short*)(lds + 18432);    // [64][72]

    const int tid   = threadIdx.x;
    const int work  = swz_work(blockIdx.x);
    const int pbase = work << 6;
    const int w0    = pbase & (WN-1);
    const int hi    = (pbase >> 7) & (HN-1);
    const int bi    = pbase >> 14;

    // ---- tap precompute: clamped corner addresses + validity-folded weights
    for (int e = tid; e < 64*NT; e += 256) {
        int pix = e / NT, n = e - pix*NT;
        float2 off = offs[(pbase + pix)*NT + n];
        float px = (float)(w0 + pix) + off.x;
        float py = (float)hi + off.y;
        float x0f = floorf(px), y0f = floorf(py);
        float fx = px - x0f,    fy = py - y0f;
        int ix0 = (int)x0f, iy0 = (int)y0f;
        int ix1 = ix0 + 1,  iy1 = iy0 + 1;
        float vx0 = (ix0 >= 0 && ix0 < WN) ? 1.f : 0.f;
        float vx1 = (ix1 >= 0 && ix1 < WN) ? 1.f : 0.f;
        float vy0 = (iy0 >= 0 && iy0 < HN) ? 1.f : 0.f;
        float vy1 = (iy1 >= 0 && iy1 < HN) ? 1.f : 0.f;
        int x0c = min(max(ix0,0),WN-1), x1c = min(max(ix1,0),WN-1);
        int y0c = min(max(iy0,0),HN-1), y1c = min(max(iy1,0),HN-1);
        tapA[e] = make_int4(y0c*WN+x0c, y0c*WN+x1c, y1c*WN+x0c, y1c*WN+x1c);
        tapW[e] = make_float4((1.f-fy)*(1.f-fx)*vy0*vx0, (1.f-fy)*fx*vy0*vx1,
                              fy*(1.f-fx)*vy1*vx0,       fy*fx*vy1*vx1);
    }

    const int lane = tid & 63;
    const int g    = tid >> 6;           // wave id 0..3
    const int q    = lane >> 4;          // quad within wave
    const int m15  = lane & 15;
    const int mpix = g*16 + m15;         // this wave's pixel-tile rows
    const float* xb = x + (size_t)bi * CN * HWN;

    floatx4 acc[4];
    #pragma unroll
    for (int f = 0; f < 4; ++f) acc[f] = (floatx4){0.f,0.f,0.f,0.f};

    for (int n = 0; n < NT; ++n) {
        __syncthreads();                 // sT safe to overwrite / taps ready
        {
            // gather: lanes = pixels (coalesced), this wave covers c=g*16..+15
            int pix = lane;
            int4   ta = tapA[pix*NT + n];
            float4 tw = tapW[pix*NT + n];
            const float* pc = xb + (g*16)*HWN;
            unsigned int packed[8];
            #pragma unroll
            for (int jj = 0; jj < 8; ++jj) {
                const float* p0 = pc + (2*jj)*HWN;
                float v0 = tw.x*p0[ta.x] + tw.y*p0[ta.y]
                         + tw.z*p0[ta.z] + tw.w*p0[ta.w];
                const float* p1 = p0 + HWN;
                float v1 = tw.x*p1[ta.x] + tw.y*p1[ta.y]
                         + tw.z*p1[ta.z] + tw.w*p1[ta.w];
                packed[jj] = (unsigned int)f2bf(v0)
                           | ((unsigned int)f2bf(v1) << 16);
            }
            int4* dst = (int4*)&sT[pix*72 + g*16];   // 16B-aligned (72*2=144)
            dst[0] = make_int4(packed[0],packed[1],packed[2],packed[3]);
            dst[1] = make_int4(packed[4],packed[5],packed[6],packed[7]);
        }
        __syncthreads();

        // MFMA: wave g computes pix rows [g*16, g*16+16) x all 64 o
        #pragma unroll
        for (int k0 = 0; k0 < 64; k0 += 32) {
            bf16x8 a = *(const bf16x8*)&sT[mpix*72 + k0 + q*8];
            #pragma unroll
            for (int f = 0; f < 4; ++f) {
                bf16x8 bfr = *(const bf16x8*)&wbf[((size_t)(n*ON + f*16 + m15))*CN + k0 + q*8];
                acc[f] = __builtin_amdgcn_mfma_f32_16x16x32_bf16(a, bfr, acc[f], 0, 0, 0);
            }
        }
    }

    // ---- epilogue: transpose through LDS for coalesced stores
    __syncthreads();
    float* tr = (float*)lds;             // [64 o][72 pix], 18432B over tap region
    #pragma unroll
    for (int f = 0; f < 4; ++f) {
        int o = f*16 + m15;
        #pragma unroll
        for (int r = 0; r < 4; ++r) {
            int pix = g*16 + q*4 + r;    // C/D layout: row=(lane>>4)*4+reg
            tr[o*72 + pix] = acc[f][r];
        }
    }
    __syncthreads();
    const int og = tid >> 6;
    float* ob = out + (((size_t)bi*ON)*HN + hi)*WN + w0;
    #pragma unroll
    for (int j = 0; j < 16; ++j) {
        int o = og*16 + j;
        ob[(size_t)o*HWN + lane] = tr[o*72 + lane];
    }
}

// ---------------------------------------------------------------------------
extern "C" void kernel_launch(void* const* d_in, const int* in_sizes, int n_in,
                              void* d_out, int out_size, void* d_ws, size_t ws_size,
                              hipStream_t stream) {
    const float* x      = (const float*)d_in[0];
    const float* w_off  = (const float*)d_in[1];
    const float* w_conv = (const float*)d_in[2];
    const float* P      = (const float*)d_in[3];
    const float* d      = (const float*)d_in[4];
    const float* Pinv   = (const float*)d_in[5];
    float* out = (float*)d_out;

    float2* offs = (float2*)d_ws;                                    // 4718592 B
    unsigned short* wbf = (unsigned short*)((char*)d_ws + 4718592);  // 73728 B

    offsets_kernel<<<1024, 256, 0, stream>>>(x, w_off, w_conv, P, d, Pinv, offs, wbf);
    deform_kernel<<<1024, 256, 0, stream>>>(x, offs, wbf, out);
}